// Round 1
// baseline (2458.001 us; speedup 1.0000x reference)
//
#include <hip/hip_runtime.h>
#include <math.h>

#define N_NODES 50000
#define N_EDGES 800000
#define HID 64
#define HEADS 4
#define HC 256
#define NEG_SLOPE 0.2f
#define LN_EPS 1e-5f

// ---------------- K1: x_l = x@W_l+b_l, x_r = x@W_r+b_r  (8 nodes/block) ----
__global__ __launch_bounds__(256) void k_node_transform(
    const float* __restrict__ x,
    const float* __restrict__ W_l, const float* __restrict__ b_l,
    const float* __restrict__ W_r, const float* __restrict__ b_r,
    float* __restrict__ x_l, float* __restrict__ x_r)
{
    __shared__ float xs[8][64];
    const int n0 = blockIdx.x * 8;
    const int t = threadIdx.x;
    for (int i = t; i < 8 * 64; i += 256) xs[i >> 6][i & 63] = x[n0 * 64 + i];
    __syncthreads();

    float accl[8], accr[8];
    const float bl = b_l[t], br = b_r[t];
#pragma unroll
    for (int n = 0; n < 8; n++) { accl[n] = bl; accr[n] = br; }
    for (int k = 0; k < 64; k++) {
        const float wl = W_l[k * 256 + t];
        const float wr = W_r[k * 256 + t];
#pragma unroll
        for (int n = 0; n < 8; n++) {
            accl[n] = fmaf(xs[n][k], wl, accl[n]);
            accr[n] = fmaf(xs[n][k], wr, accr[n]);
        }
    }
#pragma unroll
    for (int n = 0; n < 8; n++) {
        x_l[(n0 + n) * 256 + t] = accl[n];
        x_r[(n0 + n) * 256 + t] = accr[n];
    }
}

// ---------------- K2: histogram of dst ------------------------------------
__global__ __launch_bounds__(256) void k_hist(const int* __restrict__ ei, int* __restrict__ count)
{
    const int e = blockIdx.x * 256 + threadIdx.x;
    if (e < N_EDGES) atomicAdd(&count[ei[N_EDGES + e]], 1);
}

// ---------------- K3: exclusive scan (single block) ------------------------
__global__ __launch_bounds__(1024) void k_scan(const int* __restrict__ count, int* __restrict__ off)
{
    __shared__ int wsum[16];
    __shared__ int s_carry;
    const int t = threadIdx.x, lane = t & 63, wv = t >> 6;
    if (t == 0) s_carry = 0;
    __syncthreads();
    for (int base = 0; base < N_NODES; base += 8192) {
        const int idx0 = base + t * 8;
        int v[8];
#pragma unroll
        for (int j = 0; j < 8; j++) { int i = idx0 + j; v[j] = (i < N_NODES) ? count[i] : 0; }
#pragma unroll
        for (int j = 1; j < 8; j++) v[j] += v[j - 1];
        const int tot = v[7];
        int sc = tot;
#pragma unroll
        for (int s = 1; s < 64; s <<= 1) { int o = __shfl_up(sc, s, 64); if (lane >= s) sc += o; }
        if (lane == 63) wsum[wv] = sc;
        __syncthreads();
        const int carry = s_carry;
        int woff = 0;
        for (int u = 0; u < wv; u++) woff += wsum[u];
        const int ebase = carry + woff + (sc - tot);
#pragma unroll
        for (int j = 0; j < 8; j++) {
            int i = idx0 + j;
            if (i < N_NODES) off[i] = ebase + (j ? v[j - 1] : 0);
        }
        __syncthreads();
        if (t == 0) { int tt = 0; for (int u = 0; u < 16; u++) tt += wsum[u]; s_carry = carry + tt; }
        __syncthreads();
    }
    if (threadIdx.x == 0) off[N_NODES] = s_carry;
}

// ---------------- K4: scatter edge ids into CSR ----------------------------
__global__ __launch_bounds__(256) void k_scatter(
    const int* __restrict__ ei, const int* __restrict__ off,
    int* __restrict__ cursor, int* __restrict__ csr_eid)
{
    const int e = blockIdx.x * 256 + threadIdx.x;
    if (e < N_EDGES) {
        const int d = ei[N_EDGES + e];
        const int pos = off[d] + atomicAdd(&cursor[d], 1);
        csr_eid[pos] = e;
    }
}

// ---------------- K5: per-edge alpha (4 waves/block, 4 edges/wave) ---------
__global__ __launch_bounds__(256) void k_alpha(
    const int* __restrict__ ei, const float* __restrict__ edge_attr,
    const float* __restrict__ W_e, const float* __restrict__ att,
    const float* __restrict__ x_l, const float* __restrict__ x_r,
    float* __restrict__ ew, float* __restrict__ denom)
{
    const int wv = __builtin_amdgcn_readfirstlane(threadIdx.x >> 6);
    const int lane = threadIdx.x & 63;
    const int e0 = (blockIdx.x * 4 + wv) * 4;     // this wave's 4 edges
    const int h = lane >> 4;                       // head of this lane's channels
    const float4 att4 = ((const float4*)att)[lane];

    float4 acc[4];
    int dst[4];
#pragma unroll
    for (int j = 0; j < 4; j++) {
        const int e = e0 + j;
        const int s = ei[e];
        dst[j] = ei[N_EDGES + e];
        const float4 a = ((const float4*)(x_l + s * 256))[lane];
        const float4 b = ((const float4*)(x_r + dst[j] * 256))[lane];
        acc[j] = make_float4(a.x + b.x, a.y + b.y, a.z + b.z, a.w + b.w);
    }

    const float* ea0 = edge_attr + (size_t)e0 * 32;
#pragma unroll
    for (int k = 0; k < 32; k++) {
        const float4 we = ((const float4*)(W_e + k * 256))[lane];
#pragma unroll
        for (int j = 0; j < 4; j++) {
            const float eav = ea0[j * 32 + k];
            acc[j].x = fmaf(eav, we.x, acc[j].x);
            acc[j].y = fmaf(eav, we.y, acc[j].y);
            acc[j].z = fmaf(eav, we.z, acc[j].z);
            acc[j].w = fmaf(eav, we.w, acc[j].w);
        }
    }

#pragma unroll
    for (int j = 0; j < 4; j++) {
        float4 m = acc[j];
        m.x = (m.x > 0.f) ? m.x : NEG_SLOPE * m.x;
        m.y = (m.y > 0.f) ? m.y : NEG_SLOPE * m.y;
        m.z = (m.z > 0.f) ? m.z : NEG_SLOPE * m.z;
        m.w = (m.w > 0.f) ? m.w : NEG_SLOPE * m.w;
        float s = m.x * att4.x + m.y * att4.y + m.z * att4.z + m.w * att4.w;
        s += __shfl_xor(s, 1, 64);
        s += __shfl_xor(s, 2, 64);
        s += __shfl_xor(s, 4, 64);
        s += __shfl_xor(s, 8, 64);   // 16-lane group = one head
        const float wexp = __expf(fminf(s, 60.f));
        if ((lane & 15) == 0) {
            ew[(e0 + j) * 4 + h] = wexp;
            atomicAdd(&denom[dst[j] * 4 + h], wexp);
        }
    }
}

// ---------------- K6: aggregate + MLP + LN + out-GEMM (4 nodes/block) ------
__global__ __launch_bounds__(256) void k_final(
    const int* __restrict__ ei, const int* __restrict__ off, const int* __restrict__ csr_eid,
    const float* __restrict__ x, const float* __restrict__ x_l,
    const float* __restrict__ ew, const float* __restrict__ denom,
    const float* __restrict__ bias_gat,
    const float* __restrict__ W1, const float* __restrict__ b1,
    const float* __restrict__ gamma, const float* __restrict__ beta,
    const float* __restrict__ W2, const float* __restrict__ b2,
    float* __restrict__ out)
{
    __shared__ float xs[4][64];
    __shared__ float zs[4][256];
    __shared__ float redS[4][4], redQ[4][4];
    __shared__ float part[4][4][64];

    const int n0 = blockIdx.x * 4;
    const int t = threadIdx.x;
    const int lane = t & 63, wvI = t >> 6;

    for (int i = t; i < 4 * 64; i += 256) xs[i >> 6][i & 63] = x[n0 * 64 + i];
    __syncthreads();

    // xl1 = tanh(x@W1+b1), channel t, 4 nodes
    float a1[4];
    const float b1v = b1[t];
#pragma unroll
    for (int n = 0; n < 4; n++) a1[n] = b1v;
    for (int k = 0; k < 64; k++) {
        const float w1v = W1[k * 256 + t];
#pragma unroll
        for (int n = 0; n < 4; n++) a1[n] = fmaf(xs[n][k], w1v, a1[n]);
    }

    // aggregation over incoming edges (CSR), channel t
    const int hq = t >> 6;
    const float bg = bias_gat[t];
    float z[4];
#pragma unroll
    for (int n = 0; n < 4; n++) {
        const int node = n0 + n;
        float g = 0.f;
        const int s0 = off[node], s1 = off[node + 1];
        for (int p = s0; p < s1; p++) {
            const int eid = csr_eid[p];
            const int src = ei[eid];
            const float wv = ew[eid * 4 + hq];
            g = fmaf(wv, x_l[src * 256 + t], g);
        }
        const float d = denom[node * 4 + hq];
        z[n] = tanhf(a1[n]) + g / (d + 1e-16f) + bg;
    }

    // LayerNorm over 256 channels per node
    const float gm = gamma[t], bt = beta[t];
#pragma unroll
    for (int n = 0; n < 4; n++) {
        float s = z[n], q = z[n] * z[n];
#pragma unroll
        for (int m = 1; m < 64; m <<= 1) { s += __shfl_xor(s, m, 64); q += __shfl_xor(q, m, 64); }
        if (lane == 0) { redS[n][wvI] = s; redQ[n][wvI] = q; }
    }
    __syncthreads();
#pragma unroll
    for (int n = 0; n < 4; n++) {
        const float s = redS[n][0] + redS[n][1] + redS[n][2] + redS[n][3];
        const float q = redQ[n][0] + redQ[n][1] + redQ[n][2] + redQ[n][3];
        const float mu = s * (1.f / 256.f);
        const float var = q * (1.f / 256.f) - mu * mu;
        const float inv = rsqrtf(var + LN_EPS);
        zs[n][t] = (z[n] - mu) * inv * gm + bt;
    }
    __syncthreads();

    // out = tanh(z@W2 + b2): thread t -> output col j=t&63, K-chunk q=t>>6
    const int j = t & 63, q = t >> 6;
    float p[4] = {0.f, 0.f, 0.f, 0.f};
    for (int c0 = 0; c0 < 64; c0++) {
        const int c = q * 64 + c0;
        const float w2v = W2[c * 64 + j];
#pragma unroll
        for (int n = 0; n < 4; n++) p[n] = fmaf(zs[n][c], w2v, p[n]);
    }
#pragma unroll
    for (int n = 0; n < 4; n++) part[n][q][j] = p[n];
    __syncthreads();
    {
        const int n = t >> 6, jj = t & 63;
        const float s = part[n][0][jj] + part[n][1][jj] + part[n][2][jj] + part[n][3][jj];
        out[(n0 + n) * 64 + jj] = tanhf(s + b2[jj]);
    }
}

// ---------------- launcher --------------------------------------------------
extern "C" void kernel_launch(void* const* d_in, const int* in_sizes, int n_in,
                              void* d_out, int out_size, void* d_ws, size_t ws_size,
                              hipStream_t stream)
{
    const float* x         = (const float*)d_in[0];
    const int*   ei        = (const int*)d_in[1];
    const float* edge_attr = (const float*)d_in[2];
    const float* W_l       = (const float*)d_in[3];
    const float* b_l       = (const float*)d_in[4];
    const float* W_r       = (const float*)d_in[5];
    const float* b_r       = (const float*)d_in[6];
    const float* W_e       = (const float*)d_in[7];
    const float* att       = (const float*)d_in[8];
    const float* bias_gat  = (const float*)d_in[9];
    const float* W1        = (const float*)d_in[10];
    const float* b1        = (const float*)d_in[11];
    const float* gamma     = (const float*)d_in[12];
    const float* beta      = (const float*)d_in[13];
    const float* W2        = (const float*)d_in[14];
    const float* b2        = (const float*)d_in[15];
    float* out = (float*)d_out;

    float* ws    = (float*)d_ws;
    float* x_l   = ws;                                    // N*256
    float* x_r   = x_l + (size_t)N_NODES * HC;            // N*256
    float* ew    = x_r + (size_t)N_NODES * HC;            // E*4
    float* denom = ew + (size_t)N_EDGES * HEADS;          // N*4
    int* count   = (int*)(denom + (size_t)N_NODES * HEADS);  // N
    int* cursor  = count + N_NODES;                       // N
    int* off     = cursor + N_NODES;                      // N+1
    int* csr_eid = off + (N_NODES + 1);                   // E

    // zero denom + count + cursor in one shot (contiguous)
    hipMemsetAsync(denom, 0, ((size_t)N_NODES * HEADS + 2 * (size_t)N_NODES) * sizeof(float), stream);

    k_node_transform<<<N_NODES / 8, 256, 0, stream>>>(x, W_l, b_l, W_r, b_r, x_l, x_r);
    k_hist<<<(N_EDGES + 255) / 256, 256, 0, stream>>>(ei, count);
    k_scan<<<1, 1024, 0, stream>>>(count, off);
    k_scatter<<<(N_EDGES + 255) / 256, 256, 0, stream>>>(ei, off, cursor, csr_eid);
    k_alpha<<<N_EDGES / 16, 256, 0, stream>>>(ei, edge_attr, W_e, att, x_l, x_r, ew, denom);
    k_final<<<N_NODES / 4, 256, 0, stream>>>(ei, off, csr_eid, x, x_l, ew, denom,
                                             bias_gat, W1, b1, gamma, beta, W2, b2, out);
}

// Round 2
// 1554.984 us; speedup vs baseline: 1.5807x; 1.5807x over previous
//
#include <hip/hip_runtime.h>
#include <math.h>

#define N_NODES 50000
#define N_EDGES 800000
#define HID 64
#define HEADS 4
#define HC 256
#define NEG_SLOPE 0.2f
#define LN_EPS 1e-5f
#define CHUNK 256

// ---------------- K1: x_l = x@W_l+b_l, x_r = x@W_r+b_r  (8 nodes/block) ----
__global__ __launch_bounds__(256) void k_node_transform(
    const float* __restrict__ x,
    const float* __restrict__ W_l, const float* __restrict__ b_l,
    const float* __restrict__ W_r, const float* __restrict__ b_r,
    float* __restrict__ x_l, float* __restrict__ x_r)
{
    __shared__ float xs[8][64];
    const int n0 = blockIdx.x * 8;
    const int t = threadIdx.x;
    for (int i = t; i < 8 * 64; i += 256) xs[i >> 6][i & 63] = x[n0 * 64 + i];
    __syncthreads();

    float accl[8], accr[8];
    const float bl = b_l[t], br = b_r[t];
#pragma unroll
    for (int n = 0; n < 8; n++) { accl[n] = bl; accr[n] = br; }
    for (int k = 0; k < 64; k++) {
        const float wl = W_l[k * 256 + t];
        const float wr = W_r[k * 256 + t];
#pragma unroll
        for (int n = 0; n < 8; n++) {
            accl[n] = fmaf(xs[n][k], wl, accl[n]);
            accr[n] = fmaf(xs[n][k], wr, accr[n]);
        }
    }
#pragma unroll
    for (int n = 0; n < 8; n++) {
        x_l[(n0 + n) * 256 + t] = accl[n];
        x_r[(n0 + n) * 256 + t] = accr[n];
    }
}

// ---------------- K2: histogram of dst ------------------------------------
__global__ __launch_bounds__(256) void k_hist(const int* __restrict__ ei, int* __restrict__ count)
{
    const int e = blockIdx.x * 256 + threadIdx.x;
    if (e < N_EDGES) atomicAdd(&count[ei[N_EDGES + e]], 1);
}

// ---------------- K3: exclusive scan (single block) ------------------------
__global__ __launch_bounds__(1024) void k_scan(const int* __restrict__ count, int* __restrict__ off)
{
    __shared__ int wsum[16];
    __shared__ int s_carry;
    const int t = threadIdx.x, lane = t & 63, wv = t >> 6;
    if (t == 0) s_carry = 0;
    __syncthreads();
    for (int base = 0; base < N_NODES; base += 8192) {
        const int idx0 = base + t * 8;
        int v[8];
#pragma unroll
        for (int j = 0; j < 8; j++) { int i = idx0 + j; v[j] = (i < N_NODES) ? count[i] : 0; }
#pragma unroll
        for (int j = 1; j < 8; j++) v[j] += v[j - 1];
        const int tot = v[7];
        int sc = tot;
#pragma unroll
        for (int s = 1; s < 64; s <<= 1) { int o = __shfl_up(sc, s, 64); if (lane >= s) sc += o; }
        if (lane == 63) wsum[wv] = sc;
        __syncthreads();
        const int carry = s_carry;
        int woff = 0;
        for (int u = 0; u < wv; u++) woff += wsum[u];
        const int ebase = carry + woff + (sc - tot);
#pragma unroll
        for (int j = 0; j < 8; j++) {
            int i = idx0 + j;
            if (i < N_NODES) off[i] = ebase + (j ? v[j - 1] : 0);
        }
        __syncthreads();
        if (t == 0) { int tt = 0; for (int u = 0; u < 16; u++) tt += wsum[u]; s_carry = carry + tt; }
        __syncthreads();
    }
    if (threadIdx.x == 0) off[N_NODES] = s_carry;
}

// ---------------- K4: per-edge alpha + direct CSR fill ---------------------
// 4 waves/block, 4 edges/wave. Writes csr_src[pos] and UNNORMALIZED per-head
// weight ew_csr[pos*4+h] directly at the CSR position (order within a segment
// is irrelevant for the segment sum).
__global__ __launch_bounds__(256) void k_alpha(
    const int* __restrict__ ei, const float* __restrict__ edge_attr,
    const float* __restrict__ W_e, const float* __restrict__ att,
    const float* __restrict__ x_l, const float* __restrict__ x_r,
    const int* __restrict__ off, int* __restrict__ cursor,
    int* __restrict__ csr_src, float* __restrict__ ew_csr,
    float* __restrict__ denom)
{
    const int wv = __builtin_amdgcn_readfirstlane(threadIdx.x >> 6);
    const int lane = threadIdx.x & 63;
    const int e0 = (blockIdx.x * 4 + wv) * 4;     // this wave's 4 edges
    const int h = lane >> 4;                       // head of this lane's channels
    const float4 att4 = ((const float4*)att)[lane];

    float4 acc[4];
    int dstj[4], srcj[4];
#pragma unroll
    for (int j = 0; j < 4; j++) {
        const int e = e0 + j;
        srcj[j] = ei[e];
        dstj[j] = ei[N_EDGES + e];
        const float4 a = ((const float4*)(x_l + (size_t)srcj[j] * 256))[lane];
        const float4 b = ((const float4*)(x_r + (size_t)dstj[j] * 256))[lane];
        acc[j] = make_float4(a.x + b.x, a.y + b.y, a.z + b.z, a.w + b.w);
    }

    const float* ea0 = edge_attr + (size_t)e0 * 32;
#pragma unroll
    for (int k = 0; k < 32; k++) {
        const float4 we = ((const float4*)(W_e + k * 256))[lane];
#pragma unroll
        for (int j = 0; j < 4; j++) {
            const float eav = ea0[j * 32 + k];
            acc[j].x = fmaf(eav, we.x, acc[j].x);
            acc[j].y = fmaf(eav, we.y, acc[j].y);
            acc[j].z = fmaf(eav, we.z, acc[j].z);
            acc[j].w = fmaf(eav, we.w, acc[j].w);
        }
    }

#pragma unroll
    for (int j = 0; j < 4; j++) {
        float4 m = acc[j];
        m.x = (m.x > 0.f) ? m.x : NEG_SLOPE * m.x;
        m.y = (m.y > 0.f) ? m.y : NEG_SLOPE * m.y;
        m.z = (m.z > 0.f) ? m.z : NEG_SLOPE * m.z;
        m.w = (m.w > 0.f) ? m.w : NEG_SLOPE * m.w;
        float s = m.x * att4.x + m.y * att4.y + m.z * att4.z + m.w * att4.w;
        s += __shfl_xor(s, 1, 64);
        s += __shfl_xor(s, 2, 64);
        s += __shfl_xor(s, 4, 64);
        s += __shfl_xor(s, 8, 64);   // 16-lane group = one head
        const float wexp = __expf(fminf(s, 60.f));

        int pos = 0;
        if (lane == 0) pos = off[dstj[j]] + atomicAdd(&cursor[dstj[j]], 1);
        pos = __shfl(pos, 0, 64);
        if (lane == 0) csr_src[pos] = srcj[j];
        if ((lane & 15) == 0) {
            ew_csr[pos * 4 + h] = wexp;
            atomicAdd(&denom[dstj[j] * 4 + h], wexp);
        }
    }
}

// ---------------- K5: aggregate + MLP + LN + out-GEMM (4 nodes/block) ------
// Wave w owns node n0+w; lane holds channels [lane*4, lane*4+4).
// Edge metadata staged in LDS; only global op in the hot loop is the
// independent float4 gather of x_l rows.
__global__ __launch_bounds__(256, 4) void k_final(
    const int* __restrict__ off, const int* __restrict__ csr_src,
    const float* __restrict__ ew_csr, const float* __restrict__ denom,
    const float* __restrict__ x, const float* __restrict__ x_l,
    const float* __restrict__ bias_gat,
    const float* __restrict__ W1, const float* __restrict__ b1,
    const float* __restrict__ gamma, const float* __restrict__ beta,
    const float* __restrict__ W2, const float* __restrict__ b2,
    float* __restrict__ out)
{
    __shared__ float xs[4][64];
    __shared__ float zs[4][256];
    __shared__ int   s_src[CHUNK];
    __shared__ float s_w[CHUNK][4];
    __shared__ float redS[4][4], redQ[4][4];
    __shared__ float part[4][4][64];

    const int n0 = blockIdx.x * 4;
    const int t = threadIdx.x;
    const int lane = t & 63, wv = t >> 6;

    for (int i = t; i < 4 * 64; i += 256) xs[i >> 6][i & 63] = x[n0 * 64 + i];

    const int base = off[n0];
    const int cnt  = off[n0 + 4] - base;
    const int mylo = off[n0 + wv] - base;
    const int myhi = off[n0 + wv + 1] - base;
    const int hsel = lane >> 4;

    float4 g = make_float4(0.f, 0.f, 0.f, 0.f);
    for (int c0 = 0; c0 < cnt; c0 += CHUNK) {
        const int nch = min(cnt - c0, CHUNK);
        __syncthreads();
        for (int i = t; i < nch; i += 256) {
            s_src[i] = csr_src[base + c0 + i];
            ((float4*)s_w)[i] = ((const float4*)ew_csr)[base + c0 + i];
        }
        __syncthreads();
        int jlo = mylo - c0; if (jlo < 0) jlo = 0;
        int jhi = myhi - c0; if (jhi > nch) jhi = nch;
        for (int j = jlo; j < jhi; j++) {
            const int src = s_src[j];
            const float w = s_w[j][hsel];
            const float4 xv = ((const float4*)(x_l + (size_t)src * 256))[lane];
            g.x = fmaf(w, xv.x, g.x);
            g.y = fmaf(w, xv.y, g.y);
            g.z = fmaf(w, xv.z, g.z);
            g.w = fmaf(w, xv.w, g.w);
        }
    }
    // normalize once per node (linear) and park in zs
    const float inv = 1.f / (denom[(n0 + wv) * 4 + hsel] + 1e-16f);
    g.x *= inv; g.y *= inv; g.z *= inv; g.w *= inv;
    ((float4*)zs[wv])[lane] = g;
    __syncthreads();

    // xl1 = tanh(x@W1+b1), channel t, 4 nodes
    float a1[4];
    const float b1v = b1[t];
#pragma unroll
    for (int n = 0; n < 4; n++) a1[n] = b1v;
    for (int k = 0; k < 64; k++) {
        const float w1v = W1[k * 256 + t];
#pragma unroll
        for (int n = 0; n < 4; n++) a1[n] = fmaf(xs[n][k], w1v, a1[n]);
    }

    const float bg = bias_gat[t];
    float z[4];
#pragma unroll
    for (int n = 0; n < 4; n++) z[n] = tanhf(a1[n]) + zs[n][t] + bg;

    // LayerNorm over 256 channels per node
    const float gm = gamma[t], bt = beta[t];
#pragma unroll
    for (int n = 0; n < 4; n++) {
        float s = z[n], q = z[n] * z[n];
#pragma unroll
        for (int m = 1; m < 64; m <<= 1) { s += __shfl_xor(s, m, 64); q += __shfl_xor(q, m, 64); }
        if (lane == 0) { redS[n][wv] = s; redQ[n][wv] = q; }
    }
    __syncthreads();
#pragma unroll
    for (int n = 0; n < 4; n++) {
        const float s = redS[n][0] + redS[n][1] + redS[n][2] + redS[n][3];
        const float q = redQ[n][0] + redQ[n][1] + redQ[n][2] + redQ[n][3];
        const float mu = s * (1.f / 256.f);
        const float var = q * (1.f / 256.f) - mu * mu;
        const float ivn = rsqrtf(var + LN_EPS);
        zs[n][t] = (z[n] - mu) * ivn * gm + bt;
    }
    __syncthreads();

    // out = tanh(z@W2 + b2): thread t -> output col j=t&63, K-chunk q=t>>6
    const int j = t & 63, q = t >> 6;
    float p[4] = {0.f, 0.f, 0.f, 0.f};
    for (int c0 = 0; c0 < 64; c0++) {
        const int c = q * 64 + c0;
        const float w2v = W2[c * 64 + j];
#pragma unroll
        for (int n = 0; n < 4; n++) p[n] = fmaf(zs[n][c], w2v, p[n]);
    }
#pragma unroll
    for (int n = 0; n < 4; n++) part[n][q][j] = p[n];
    __syncthreads();
    {
        const int n = t >> 6, jj = t & 63;
        const float s = part[n][0][jj] + part[n][1][jj] + part[n][2][jj] + part[n][3][jj];
        out[(n0 + n) * 64 + jj] = tanhf(s + b2[jj]);
    }
}

// ---------------- launcher --------------------------------------------------
extern "C" void kernel_launch(void* const* d_in, const int* in_sizes, int n_in,
                              void* d_out, int out_size, void* d_ws, size_t ws_size,
                              hipStream_t stream)
{
    const float* x         = (const float*)d_in[0];
    const int*   ei        = (const int*)d_in[1];
    const float* edge_attr = (const float*)d_in[2];
    const float* W_l       = (const float*)d_in[3];
    const float* b_l       = (const float*)d_in[4];
    const float* W_r       = (const float*)d_in[5];
    const float* b_r       = (const float*)d_in[6];
    const float* W_e       = (const float*)d_in[7];
    const float* att       = (const float*)d_in[8];
    const float* bias_gat  = (const float*)d_in[9];
    const float* W1        = (const float*)d_in[10];
    const float* b1        = (const float*)d_in[11];
    const float* gamma     = (const float*)d_in[12];
    const float* beta      = (const float*)d_in[13];
    const float* W2        = (const float*)d_in[14];
    const float* b2        = (const float*)d_in[15];
    float* out = (float*)d_out;

    float* ws      = (float*)d_ws;
    float* x_l     = ws;                                     // N*256
    float* x_r     = x_l + (size_t)N_NODES * HC;             // N*256
    float* ew_csr  = x_r + (size_t)N_NODES * HC;             // E*4
    float* denom   = ew_csr + (size_t)N_EDGES * HEADS;       // N*4
    int* count     = (int*)(denom + (size_t)N_NODES * HEADS);// N
    int* cursor    = count + N_NODES;                        // N
    int* off       = cursor + N_NODES;                       // N+1
    int* csr_src   = off + (N_NODES + 1);                    // E

    // zero denom + count + cursor in one shot (contiguous)
    hipMemsetAsync(denom, 0, ((size_t)N_NODES * HEADS + 2 * (size_t)N_NODES) * sizeof(float), stream);

    k_node_transform<<<N_NODES / 8, 256, 0, stream>>>(x, W_l, b_l, W_r, b_r, x_l, x_r);
    k_hist<<<(N_EDGES + 255) / 256, 256, 0, stream>>>(ei, count);
    k_scan<<<1, 1024, 0, stream>>>(count, off);
    k_alpha<<<N_EDGES / 16, 256, 0, stream>>>(ei, edge_attr, W_e, att, x_l, x_r,
                                              off, cursor, csr_src, ew_csr, denom);
    k_final<<<N_NODES / 4, 256, 0, stream>>>(off, csr_src, ew_csr, denom, x, x_l,
                                             bias_gat, W1, b1, gamma, beta, W2, b2, out);
}

// Round 3
// 1261.855 us; speedup vs baseline: 1.9479x; 1.2323x over previous
//
#include <hip/hip_runtime.h>
#include <math.h>

#define N_NODES 50000
#define N_EDGES 800000
#define HID 64
#define HEADS 4
#define HC 256
#define NEG_SLOPE 0.2f
#define LN_EPS 1e-5f
#define CHUNK 256
#define EPW 8   // edges per wave in k_alpha

__device__ __forceinline__ float bf2f(unsigned short u) {
    return __uint_as_float(((unsigned int)u) << 16);
}
__device__ __forceinline__ unsigned short f2bf(float f) {
    unsigned int u = __float_as_uint(f);
    u = (u + 0x7fffu + ((u >> 16) & 1u)) >> 16;   // RNE
    return (unsigned short)u;
}

// ---------------- K1: x_l(fp32) + xl_bf + xr_bf (8 nodes/block) ------------
__global__ __launch_bounds__(256) void k_node_transform(
    const float* __restrict__ x,
    const float* __restrict__ W_l, const float* __restrict__ b_l,
    const float* __restrict__ W_r, const float* __restrict__ b_r,
    float* __restrict__ x_l, unsigned short* __restrict__ xl_bf,
    unsigned short* __restrict__ xr_bf)
{
    __shared__ float xs[8][64];
    const int n0 = blockIdx.x * 8;
    const int t = threadIdx.x;
    for (int i = t; i < 8 * 64; i += 256) xs[i >> 6][i & 63] = x[n0 * 64 + i];
    __syncthreads();

    float accl[8], accr[8];
    const float bl = b_l[t], br = b_r[t];
#pragma unroll
    for (int n = 0; n < 8; n++) { accl[n] = bl; accr[n] = br; }
    for (int k = 0; k < 64; k++) {
        const float wl = W_l[k * 256 + t];
        const float wr = W_r[k * 256 + t];
#pragma unroll
        for (int n = 0; n < 8; n++) {
            accl[n] = fmaf(xs[n][k], wl, accl[n]);
            accr[n] = fmaf(xs[n][k], wr, accr[n]);
        }
    }
#pragma unroll
    for (int n = 0; n < 8; n++) {
        x_l[(n0 + n) * 256 + t] = accl[n];
        xl_bf[(n0 + n) * 256 + t] = f2bf(accl[n]);
        xr_bf[(n0 + n) * 256 + t] = f2bf(accr[n]);
    }
}

// ---------------- K2: histogram of dst ------------------------------------
__global__ __launch_bounds__(256) void k_hist(const int* __restrict__ ei, int* __restrict__ count)
{
    const int e = blockIdx.x * 256 + threadIdx.x;
    if (e < N_EDGES) atomicAdd(&count[ei[N_EDGES + e]], 1);
}

// ---------------- K3: exclusive scan (single block) ------------------------
__global__ __launch_bounds__(1024) void k_scan(const int* __restrict__ count, int* __restrict__ off)
{
    __shared__ int wsum[16];
    __shared__ int s_carry;
    const int t = threadIdx.x, lane = t & 63, wv = t >> 6;
    if (t == 0) s_carry = 0;
    __syncthreads();
    for (int base = 0; base < N_NODES; base += 8192) {
        const int idx0 = base + t * 8;
        int v[8];
#pragma unroll
        for (int j = 0; j < 8; j++) { int i = idx0 + j; v[j] = (i < N_NODES) ? count[i] : 0; }
#pragma unroll
        for (int j = 1; j < 8; j++) v[j] += v[j - 1];
        const int tot = v[7];
        int sc = tot;
#pragma unroll
        for (int s = 1; s < 64; s <<= 1) { int o = __shfl_up(sc, s, 64); if (lane >= s) sc += o; }
        if (lane == 63) wsum[wv] = sc;
        __syncthreads();
        const int carry = s_carry;
        int woff = 0;
        for (int u = 0; u < wv; u++) woff += wsum[u];
        const int ebase = carry + woff + (sc - tot);
#pragma unroll
        for (int j = 0; j < 8; j++) {
            int i = idx0 + j;
            if (i < N_NODES) off[i] = ebase + (j ? v[j - 1] : 0);
        }
        __syncthreads();
        if (t == 0) { int tt = 0; for (int u = 0; u < 16; u++) tt += wsum[u]; s_carry = carry + tt; }
        __syncthreads();
    }
    if (threadIdx.x == 0) off[N_NODES] = s_carry;
}

// ---------------- K4: scatter edge ids / src / dst into CSR slots ----------
__global__ __launch_bounds__(256) void k_scatter(
    const int* __restrict__ ei, const int* __restrict__ off, int* __restrict__ cursor,
    int* __restrict__ csr_src, int* __restrict__ dst_csr, int* __restrict__ eid_csr)
{
    const int e = blockIdx.x * 256 + threadIdx.x;
    if (e < N_EDGES) {
        const int s = ei[e];
        const int d = ei[N_EDGES + e];
        const int pos = off[d] + atomicAdd(&cursor[d], 1);
        csr_src[pos] = s;
        dst_csr[pos] = d;
        eid_csr[pos] = e;
    }
}

// ---------------- K5: per-edge alpha, CSR order, atomic-free ---------------
// 4 waves/block, EPW edges/wave. bf16 row gathers; x_r row reuse via dst
// grouping; edge_attr via wave-uniform scalar loads; contiguous ew writes.
__global__ __launch_bounds__(256) void k_alpha(
    const int* __restrict__ csr_src, const int* __restrict__ dst_csr,
    const int* __restrict__ eid_csr, const float* __restrict__ edge_attr,
    const float* __restrict__ W_e, const float* __restrict__ att,
    const unsigned short* __restrict__ xl_bf, const unsigned short* __restrict__ xr_bf,
    float* __restrict__ ew_csr)
{
    const int wv = __builtin_amdgcn_readfirstlane(threadIdx.x >> 6);
    const int lane = threadIdx.x & 63;
    const int p0 = (blockIdx.x * 4 + wv) * EPW;
    const int h = lane >> 4;
    const float4 att4 = ((const float4*)att)[lane];

    int eidj[EPW];
    float4 acc[EPW];
#pragma unroll
    for (int j = 0; j < EPW; j++) {
        const int p = p0 + j;
        const int src = csr_src[p];
        const int dst = dst_csr[p];
        eidj[j] = eid_csr[p];
        const ushort4 a = ((const ushort4*)(xl_bf + (size_t)src * 256))[lane];
        const ushort4 b = ((const ushort4*)(xr_bf + (size_t)dst * 256))[lane];
        acc[j].x = bf2f(a.x) + bf2f(b.x);
        acc[j].y = bf2f(a.y) + bf2f(b.y);
        acc[j].z = bf2f(a.z) + bf2f(b.z);
        acc[j].w = bf2f(a.w) + bf2f(b.w);
    }

    for (int k = 0; k < 32; k++) {
        const float4 we = ((const float4*)(W_e + k * 256))[lane];
#pragma unroll
        for (int j = 0; j < EPW; j++) {
            const float eav = edge_attr[(size_t)eidj[j] * 32 + k];
            acc[j].x = fmaf(eav, we.x, acc[j].x);
            acc[j].y = fmaf(eav, we.y, acc[j].y);
            acc[j].z = fmaf(eav, we.z, acc[j].z);
            acc[j].w = fmaf(eav, we.w, acc[j].w);
        }
    }

#pragma unroll
    for (int j = 0; j < EPW; j++) {
        float4 m = acc[j];
        m.x = (m.x > 0.f) ? m.x : NEG_SLOPE * m.x;
        m.y = (m.y > 0.f) ? m.y : NEG_SLOPE * m.y;
        m.z = (m.z > 0.f) ? m.z : NEG_SLOPE * m.z;
        m.w = (m.w > 0.f) ? m.w : NEG_SLOPE * m.w;
        float s = m.x * att4.x + m.y * att4.y + m.z * att4.z + m.w * att4.w;
        s += __shfl_xor(s, 1, 64);
        s += __shfl_xor(s, 2, 64);
        s += __shfl_xor(s, 4, 64);
        s += __shfl_xor(s, 8, 64);   // 16-lane group = one head
        const float wexp = __expf(fminf(s, 60.f));
        if ((lane & 15) == 0) ew_csr[(p0 + j) * 4 + h] = wexp;
    }
}

// ---------------- K6: aggregate + MLP + LN + out-GEMM (4 nodes/block) ------
__global__ __launch_bounds__(256, 4) void k_final(
    const int* __restrict__ off, const int* __restrict__ csr_src,
    const float* __restrict__ ew_csr,
    const float* __restrict__ x, const float* __restrict__ x_l,
    const float* __restrict__ bias_gat,
    const float* __restrict__ W1, const float* __restrict__ b1,
    const float* __restrict__ gamma, const float* __restrict__ beta,
    const float* __restrict__ W2, const float* __restrict__ b2,
    float* __restrict__ out)
{
    __shared__ float xs[4][64];
    __shared__ float zs[4][256];
    __shared__ int   s_src[CHUNK];
    __shared__ float s_w[CHUNK][4];
    __shared__ float redS[4][4], redQ[4][4];
    __shared__ float part[4][4][64];

    const int n0 = blockIdx.x * 4;
    const int t = threadIdx.x;
    const int lane = t & 63, wv = t >> 6;

    for (int i = t; i < 4 * 64; i += 256) xs[i >> 6][i & 63] = x[n0 * 64 + i];

    const int base = off[n0];
    const int cnt  = off[n0 + 4] - base;
    const int mylo = off[n0 + wv] - base;
    const int myhi = off[n0 + wv + 1] - base;
    const int hsel = lane >> 4;

    float4 g = make_float4(0.f, 0.f, 0.f, 0.f);
    float dsum = 0.f;
    for (int c0 = 0; c0 < cnt; c0 += CHUNK) {
        const int nch = min(cnt - c0, CHUNK);
        __syncthreads();
        for (int i = t; i < nch; i += 256) {
            s_src[i] = csr_src[base + c0 + i];
            ((float4*)s_w)[i] = ((const float4*)ew_csr)[base + c0 + i];
        }
        __syncthreads();
        int jlo = mylo - c0; if (jlo < 0) jlo = 0;
        int jhi = myhi - c0; if (jhi > nch) jhi = nch;
        for (int j = jlo; j < jhi; j++) {
            const int src = s_src[j];
            const float w = s_w[j][hsel];
            dsum += w;
            const float4 xv = ((const float4*)(x_l + (size_t)src * 256))[lane];
            g.x = fmaf(w, xv.x, g.x);
            g.y = fmaf(w, xv.y, g.y);
            g.z = fmaf(w, xv.z, g.z);
            g.w = fmaf(w, xv.w, g.w);
        }
    }
    // normalize once per node (linear) and park in zs
    const float inv = 1.f / (dsum + 1e-16f);
    g.x *= inv; g.y *= inv; g.z *= inv; g.w *= inv;
    ((float4*)zs[wv])[lane] = g;
    __syncthreads();

    // xl1 = tanh(x@W1+b1), channel t, 4 nodes
    float a1[4];
    const float b1v = b1[t];
#pragma unroll
    for (int n = 0; n < 4; n++) a1[n] = b1v;
    for (int k = 0; k < 64; k++) {
        const float w1v = W1[k * 256 + t];
#pragma unroll
        for (int n = 0; n < 4; n++) a1[n] = fmaf(xs[n][k], w1v, a1[n]);
    }

    const float bg = bias_gat[t];
    float z[4];
#pragma unroll
    for (int n = 0; n < 4; n++) z[n] = tanhf(a1[n]) + zs[n][t] + bg;

    // LayerNorm over 256 channels per node
    const float gm = gamma[t], bt = beta[t];
#pragma unroll
    for (int n = 0; n < 4; n++) {
        float s = z[n], q = z[n] * z[n];
#pragma unroll
        for (int m = 1; m < 64; m <<= 1) { s += __shfl_xor(s, m, 64); q += __shfl_xor(q, m, 64); }
        if (lane == 0) { redS[n][wv] = s; redQ[n][wv] = q; }
    }
    __syncthreads();
#pragma unroll
    for (int n = 0; n < 4; n++) {
        const float s = redS[n][0] + redS[n][1] + redS[n][2] + redS[n][3];
        const float q = redQ[n][0] + redQ[n][1] + redQ[n][2] + redQ[n][3];
        const float mu = s * (1.f / 256.f);
        const float var = q * (1.f / 256.f) - mu * mu;
        const float ivn = rsqrtf(var + LN_EPS);
        zs[n][t] = (z[n] - mu) * ivn * gm + bt;
    }
    __syncthreads();

    // out = tanh(z@W2 + b2): thread t -> output col j=t&63, K-chunk q=t>>6
    const int j = t & 63, q = t >> 6;
    float p[4] = {0.f, 0.f, 0.f, 0.f};
    for (int c0 = 0; c0 < 64; c0++) {
        const int c = q * 64 + c0;
        const float w2v = W2[c * 64 + j];
#pragma unroll
        for (int n = 0; n < 4; n++) p[n] = fmaf(zs[n][c], w2v, p[n]);
    }
#pragma unroll
    for (int n = 0; n < 4; n++) part[n][q][j] = p[n];
    __syncthreads();
    {
        const int n = t >> 6, jj = t & 63;
        const float s = part[n][0][jj] + part[n][1][jj] + part[n][2][jj] + part[n][3][jj];
        out[(n0 + n) * 64 + jj] = tanhf(s + b2[jj]);
    }
}

// ---------------- launcher --------------------------------------------------
extern "C" void kernel_launch(void* const* d_in, const int* in_sizes, int n_in,
                              void* d_out, int out_size, void* d_ws, size_t ws_size,
                              hipStream_t stream)
{
    const float* x         = (const float*)d_in[0];
    const int*   ei        = (const int*)d_in[1];
    const float* edge_attr = (const float*)d_in[2];
    const float* W_l       = (const float*)d_in[3];
    const float* b_l       = (const float*)d_in[4];
    const float* W_r       = (const float*)d_in[5];
    const float* b_r       = (const float*)d_in[6];
    const float* W_e       = (const float*)d_in[7];
    const float* att       = (const float*)d_in[8];
    const float* bias_gat  = (const float*)d_in[9];
    const float* W1        = (const float*)d_in[10];
    const float* b1        = (const float*)d_in[11];
    const float* gamma     = (const float*)d_in[12];
    const float* beta      = (const float*)d_in[13];
    const float* W2        = (const float*)d_in[14];
    const float* b2        = (const float*)d_in[15];
    float* out = (float*)d_out;

    char* ws = (char*)d_ws;
    float* x_l            = (float*)ws;                      ws += (size_t)N_NODES * HC * 4;  // 51.2 MB
    unsigned short* xl_bf = (unsigned short*)ws;             ws += (size_t)N_NODES * HC * 2;  // 25.6 MB
    unsigned short* xr_bf = (unsigned short*)ws;             ws += (size_t)N_NODES * HC * 2;  // 25.6 MB
    float* ew_csr         = (float*)ws;                      ws += (size_t)N_EDGES * HEADS * 4; // 12.8 MB
    int* csr_src          = (int*)ws;                        ws += (size_t)N_EDGES * 4;
    int* dst_csr          = (int*)ws;                        ws += (size_t)N_EDGES * 4;
    int* eid_csr          = (int*)ws;                        ws += (size_t)N_EDGES * 4;
    int* count            = (int*)ws;                        ws += (size_t)N_NODES * 4;
    int* cursor           = (int*)ws;                        ws += (size_t)N_NODES * 4;
    int* off              = (int*)ws;                        ws += (size_t)(N_NODES + 1) * 4;

    // zero count + cursor (contiguous)
    hipMemsetAsync(count, 0, 2 * (size_t)N_NODES * sizeof(int), stream);

    k_node_transform<<<N_NODES / 8, 256, 0, stream>>>(x, W_l, b_l, W_r, b_r, x_l, xl_bf, xr_bf);
    k_hist<<<(N_EDGES + 255) / 256, 256, 0, stream>>>(ei, count);
    k_scan<<<1, 1024, 0, stream>>>(count, off);
    k_scatter<<<(N_EDGES + 255) / 256, 256, 0, stream>>>(ei, off, cursor, csr_src, dst_csr, eid_csr);
    k_alpha<<<N_EDGES / (4 * EPW), 256, 0, stream>>>(csr_src, dst_csr, eid_csr, edge_attr,
                                                     W_e, att, xl_bf, xr_bf, ew_csr);
    k_final<<<N_NODES / 4, 256, 0, stream>>>(off, csr_src, ew_csr, x, x_l,
                                             bias_gat, W1, b1, gamma, beta, W2, b2, out);
}